// Round 6
// baseline (242.012 us; speedup 1.0000x reference)
//
#include <hip/hip_runtime.h>
#include <hip/hip_bf16.h>
#include <float.h>

#define B_    16
#define N1_   4096
#define N2_   1024
#define C2_   256
#define OUT_  256
#define K_    4096    // GEMM K == N1
#define SPLITK 8
#define KCH_  (K_ / SPLITK)     // 512
#define ZSLAB 1048576           // floats per partial slab (16*256*256)

typedef short short8 __attribute__((ext_vector_type(8)));
typedef float float4v __attribute__((ext_vector_type(4)));

static __device__ __forceinline__ unsigned short f32_to_bf16_bits(float v) {
    __hip_bfloat16 h = __float2bfloat16(v);
    return *(unsigned short*)&h;
}

static __device__ __forceinline__ void gload16(const void* g, void* l) {
    __builtin_amdgcn_global_load_lds(
        (const __attribute__((address_space(1))) unsigned int*)g,
        (__attribute__((address_space(3))) unsigned int*)l, 16, 0, 0);
}

// ---------------------------------------------------------------------------
// Fused (w1cvt + knn + interp) in ONE dispatch, block-role branch.
// R17 XCD-locality remap (T1): b = ((rem>>9)<<3)|(rem&7) pins all 64
// blocks of batch b to XCD b&7 -> x2[b] L2-resident for the phase-B gather.
// Unchanged in R19.
// ---------------------------------------------------------------------------
#define TPAD 65
struct KnnSh {
    float4 pts[16][65];       // per-slice padded candidates   16.64 KB
    float  pf[64][49];        // per-slice packed top-3 (q-major) 12.54 KB
};
union ShUnion {
    KnnSh a;
    unsigned short tile[C2_][TPAD];   // transpose tile  33.3 KB
};

__global__ __launch_bounds__(256) void knn_interp_kernel(
    const float* __restrict__ xyz1,
    const float* __restrict__ xyz2,
    const float* __restrict__ x2,
    unsigned short* __restrict__ interp_t,
    const float* __restrict__ W1,
    unsigned short* __restrict__ W1b,
    float* __restrict__ accum)
{
    __shared__ ShUnion sh;
    __shared__ float rw[64][3];
    __shared__ int   ri[64][3];

    const int bid = blockIdx.x;
    const int t   = threadIdx.x;

    if (bid < 1024) {   // ---- role: W1 convert (+ accum zero) ----
        if (bid == 0) {
            accum[t] = 0.0f;
            accum[256 + t] = 0.0f;
        }
        const int i = (bid * 256 + t) * 4;
        float4 v = *(const float4*)(W1 + i);
        ushort4 o;
        o.x = f32_to_bf16_bits(v.x);
        o.y = f32_to_bf16_bits(v.y);
        o.z = f32_to_bf16_bits(v.z);
        o.w = f32_to_bf16_bits(v.w);
        *(ushort4*)(W1b + i) = o;
        return;
    }

    // ---- role: knn + interp ----
    // XCD-pinned decode: XCD = bid%8 = rem%8 = b&7 -> same-batch blocks
    // share one XCD's L2 for the x2 gather.
    const int rem = bid - 1024;
    const int b   = ((rem >> 9) << 3) | (rem & 7);
    const int n0  = ((rem >> 3) & 63) * 64;
    const int w   = t >> 6;
    const int l   = t & 63;

    for (int r = 0; r < 4; ++r) {
        int j = r * 256 + t;
        const float* p = xyz2 + ((size_t)b * N2_ + j) * 3;
        float x = p[0], y = p[1], z = p[2];
        sh.a.pts[j >> 6][j & 63] = make_float4(x, y, z, 0.5f * ((x * x + y * y) + z * z));
    }
    __syncthreads();

    const int qg    = l & 15;           // query group: 4 queries per lane
    const int slice = (w << 2) | (l >> 4);   // 16 slices of 64 candidates
    const int jbase = slice << 6;

    // load this lane's 4 queries (12 consecutive floats, 48B aligned)
    const float* qb = xyz1 + ((size_t)b * N1_ + n0 + qg * 4) * 3;
    float4 v0 = ((const float4*)qb)[0];
    float4 v1 = ((const float4*)qb)[1];
    float4 v2 = ((const float4*)qb)[2];
    float qx[4] = {v0.x, v0.w, v1.z, v2.y};
    float qy[4] = {v0.y, v1.x, v1.w, v2.z};
    float qz[4] = {v0.z, v1.y, v2.x, v2.w};

    float ns0[4], ns1[4], ns2[4], ss[4], f[4][3];
    #pragma unroll
    for (int i = 0; i < 4; ++i) {
        ns0[i] = -qx[i]; ns1[i] = -qy[i]; ns2[i] = -qz[i];
        ss[i]  = (qx[i] * qx[i] + qy[i] * qy[i]) + qz[i] * qz[i];
        f[i][0] = FLT_MAX; f[i][1] = FLT_MAX; f[i][2] = FLT_MAX;
    }

    #pragma unroll 2
    for (int jj = 0; jj < 64; ++jj) {
        float4 pq = sh.a.pts[slice][jj];
        int j = jbase + jj;
        #pragma unroll
        for (int i = 0; i < 4; ++i) {
            float acc = fmaf(ns0[i], pq.x, pq.w);
            acc = fmaf(ns1[i], pq.y, acc);
            acc = fmaf(ns2[i], pq.z, acc);
            float dk = fmaxf(fmaf(2.0f, acc, ss[i]), 0.0f);
            float fp = __int_as_float((__float_as_int(dk) & 0xFFFFFC00) | j);
            float nf0 = fminf(fp, f[i][0]);
            float nf1 = __builtin_amdgcn_fmed3f(fp, f[i][0], f[i][1]);
            float nf2 = fminf(f[i][2], fmaxf(fp, f[i][1]));
            f[i][0] = nf0; f[i][1] = nf1; f[i][2] = nf2;
        }
    }

    #pragma unroll
    for (int i = 0; i < 4; ++i)
    #pragma unroll
    for (int r = 0; r < 3; ++r)
        sh.a.pf[qg * 4 + i][slice * 3 + r] = f[i][r];
    __syncthreads();

    if (w == 0) {
        float g0 = FLT_MAX, g1 = FLT_MAX, g2 = FLT_MAX;
        #pragma unroll 4
        for (int s = 0; s < 16; ++s)
        #pragma unroll
        for (int r = 0; r < 3; ++r) {
            float fp = sh.a.pf[l][s * 3 + r];
            float n0v = fminf(fp, g0);
            float n1v = __builtin_amdgcn_fmed3f(fp, g0, g1);
            float n2v = fminf(g2, fmaxf(fp, g1));
            g0 = n0v; g1 = n1v; g2 = n2v;
        }
        int j0 = __float_as_int(g0) & 1023;
        int j1 = __float_as_int(g1) & 1023;
        int j2 = __float_as_int(g2) & 1023;
        const float4 p0 = sh.a.pts[j0 >> 6][j0 & 63];
        const float4 p1 = sh.a.pts[j1 >> 6][j1 & 63];
        const float4 p2 = sh.a.pts[j2 >> 6][j2 & 63];
        // recompute exact distances for THIS query (lane l = local query id)
        const float* q = xyz1 + ((size_t)b * N1_ + n0 + l) * 3;
        const float s0 = q[0], s1 = q[1], s2 = q[2];
        const float ssl = (s0 * s0 + s1 * s1) + s2 * s2;
        float dd0 = ssl + 2.0f * (p0.w - ((s0 * p0.x + s1 * p0.y) + s2 * p0.z));
        float dd1 = ssl + 2.0f * (p1.w - ((s0 * p1.x + s1 * p1.y) + s2 * p1.z));
        float dd2 = ssl + 2.0f * (p2.w - ((s0 * p2.x + s1 * p2.y) + s2 * p2.z));
        float r0 = 1.0f / (dd0 + 1e-8f);
        float r1 = 1.0f / (dd1 + 1e-8f);
        float r2 = 1.0f / (dd2 + 1e-8f);
        float sden = (r0 + r1) + r2;
        rw[l][0] = r0 / sden;  rw[l][1] = r1 / sden;  rw[l][2] = r2 / sden;
        ri[l][0] = j0;         ri[l][1] = j1;         ri[l][2] = j2;
    }
    __syncthreads();   // rw/ri ready; pts/pf dead -> tile may alias

    for (int p = 0; p < 16; ++p) {
        int nl = p * 4 + w;
        float w0 = rw[nl][0], w1 = rw[nl][1], w2 = rw[nl][2];
        int i0g = ri[nl][0], i1g = ri[nl][1], i2g = ri[nl][2];
        const float4 va = ((const float4*)(x2 + ((size_t)b * N2_ + i0g) * C2_))[l];
        const float4 vb = ((const float4*)(x2 + ((size_t)b * N2_ + i1g) * C2_))[l];
        const float4 vc = ((const float4*)(x2 + ((size_t)b * N2_ + i2g) * C2_))[l];
        float fa[4] = {va.x, va.y, va.z, va.w};
        float fb[4] = {vb.x, vb.y, vb.z, vb.w};
        float fc[4] = {vc.x, vc.y, vc.z, vc.w};
        #pragma unroll
        for (int i = 0; i < 4; ++i) {
            float v = w0 * fa[i];
            v = fmaf(w1, fb[i], v);
            v = fmaf(w2, fc[i], v);
            sh.tile[l * 4 + i][nl] = f32_to_bf16_bits(v);
        }
    }
    __syncthreads();

    for (int r = 0; r < 64; ++r) {
        int c = r * 4 + w;
        interp_t[((size_t)b * C2_ + c) * K_ + n0 + l] = sh.tile[c][l];
    }
}

// ---------------------------------------------------------------------------
// Kernel 3: split-K GEMM, tile 128(o) x 64(c), BK=64 -> 8 iterations.
// global_load_lds width-16 into LINEAR LDS with XOR chunk-swizzle (R16).
// R17 grid (4c, 128bk, 2o): o-tile partners 512 apart (== 0 mod 8) -> same
// XCD -> B fetched once. Unchanged in R19.
// ---------------------------------------------------------------------------
__global__ __launch_bounds__(256) void gemm_kernel(
    const unsigned short* __restrict__ W1b,
    const unsigned short* __restrict__ interp_t,
    float* __restrict__ Zp)
{
    __shared__ unsigned short Alds[128 * 64];   // 16 KB linear
    __shared__ unsigned short Blds[64 * 64];    //  8 KB linear
    const int b  = blockIdx.y >> 3;
    const int kc = blockIdx.y & 7;
    const int o0 = blockIdx.z * 128;
    const int c0 = blockIdx.x * 64;
    const int t = threadIdx.x;
    const int w = t >> 6, l = t & 63;
    const int ob = (w >> 1) * 64, cb = (w & 1) * 32;
    const int m = l & 15, kq = l >> 4;

    const int rs  = l >> 3;        // row within 8-row segment
    const int ch  = l & 7;         // 16B chunk within 128B row
    const int sch = ch ^ rs;       // swizzled source chunk

    const unsigned short* Abase = W1b + (size_t)o0 * K_ + kc * KCH_ + sch * 8;
    const unsigned short* Bbase = interp_t + ((size_t)b * C2_ + c0) * K_ + kc * KCH_ + sch * 8;

    float4v acc[4][2] = {};

    for (int kk = 0; kk < KCH_; kk += 64) {
        // stage A: 16 segments of 1KB, wave w does s = w, w+4, w+8, w+12
        #pragma unroll
        for (int i = 0; i < 4; ++i) {
            int s = w + i * 4;
            gload16(Abase + (size_t)(s * 8 + rs) * K_ + kk, &Alds[s * 512 + l * 8]);
        }
        // stage B: 8 segments, wave w does s = w, w+4
        #pragma unroll
        for (int i = 0; i < 2; ++i) {
            int s = w + i * 4;
            gload16(Bbase + (size_t)(s * 8 + rs) * K_ + kk, &Blds[s * 512 + l * 8]);
        }
        __syncthreads();

        #pragma unroll
        for (int ks = 0; ks < 64; ks += 32) {
            const int swz = ((kq + (ks >> 3)) ^ (m & 7)) << 3;
            short8 bf0 = *(const short8*)&Blds[(cb + m) * 64 + swz];
            short8 bf1 = *(const short8*)&Blds[(cb + 16 + m) * 64 + swz];
            #pragma unroll
            for (int mi = 0; mi < 4; ++mi) {
                short8 af = *(const short8*)&Alds[(ob + mi * 16 + m) * 64 + swz];
                acc[mi][0] = __builtin_amdgcn_mfma_f32_16x16x32_bf16(af, bf0, acc[mi][0], 0, 0, 0);
                acc[mi][1] = __builtin_amdgcn_mfma_f32_16x16x32_bf16(af, bf1, acc[mi][1], 0, 0, 0);
            }
        }
        __syncthreads();
    }

    float* Zslab = Zp + (size_t)kc * ZSLAB;
    #pragma unroll
    for (int mi = 0; mi < 4; ++mi)
    #pragma unroll
    for (int ni = 0; ni < 2; ++ni)
    #pragma unroll
    for (int r = 0; r < 4; ++r) {
        int o = o0 + ob + mi * 16 + kq * 4 + r;
        int c = c0 + cb + ni * 16 + m;
        Zslab[((size_t)b * OUT_ + o) * C2_ + c] = acc[mi][ni][r];
    }
}

// ---------------------------------------------------------------------------
// Kernel 4 (R19): bandwidth-shaped reduce + stats.
// R18's counters exposed the old reduce as ~40-45us latency-starved
// (1 block/CU, 128 scalar loads/thread, 435 GB/s, VALUBusy 1%). Rebuild:
// 1024 blocks x 256 threads, ONE float4 per thread (262144 = exact cover),
// 8 coalesced float4 slab loads (1 KB/wave/slab), bias-first add order
// preserved per element. 16 waves/CU x 8 KB in flight >> the ~9 KB/CU
// Little's-law requirement -> streams at L3/HBM BW. Stats: within a block
// i4&63 == t&63, so threads t,t+64,t+128,t+192 share 4 channels -> 8 KB LDS
// cross-group reduce, then 512 atomicAdds/block (524K total over 512 addrs).
// ---------------------------------------------------------------------------
__global__ __launch_bounds__(256) void reduce_stats_kernel(
    float* __restrict__ Zp, const float* __restrict__ b1,
    float* __restrict__ accum)
{
    __shared__ float red_s[256][4];
    __shared__ float red_q[256][4];
    const int t  = threadIdx.x;
    const int i4 = blockIdx.x * 256 + t;       // float4 index, 0..262143
    const int o  = (i4 >> 6) & 255;

    float bb = b1[o];
    float4 v = make_float4(bb, bb, bb, bb);
    #pragma unroll
    for (int sl = 0; sl < SPLITK; ++sl) {
        float4 p = *((const float4*)Zp + (size_t)sl * (ZSLAB / 4) + i4);
        v.x += p.x; v.y += p.y; v.z += p.z; v.w += p.w;
    }
    *((float4*)Zp + i4) = v;                   // final Z into slab 0

    red_s[t][0] = v.x;       red_s[t][1] = v.y;
    red_s[t][2] = v.z;       red_s[t][3] = v.w;
    red_q[t][0] = v.x * v.x; red_q[t][1] = v.y * v.y;
    red_q[t][2] = v.z * v.z; red_q[t][3] = v.w * v.w;
    __syncthreads();

    if (t < 64) {
        #pragma unroll
        for (int j = 0; j < 4; ++j) {
            float s = red_s[t][j] + red_s[t + 64][j] + red_s[t + 128][j] + red_s[t + 192][j];
            float q = red_q[t][j] + red_q[t + 64][j] + red_q[t + 128][j] + red_q[t + 192][j];
            atomicAdd(&accum[t * 4 + j], s);
            atomicAdd(&accum[C2_ + t * 4 + j], q);
        }
    }
}

// ---------------------------------------------------------------------------
// Kernel 5: normalize + affine + ReLU + f32 store (reads final Z = slab 0).
// Restored verbatim from R17.
// ---------------------------------------------------------------------------
__global__ __launch_bounds__(256) void bn_kernel(
    const float* __restrict__ Z, const float* __restrict__ accum,
    const float* __restrict__ gamma, const float* __restrict__ beta,
    float* __restrict__ out)
{
    const int i = (blockIdx.x * 256 + threadIdx.x) * 4;
    float4 z = *(const float4*)(Z + i);
    float vals[4] = {z.x, z.y, z.z, z.w};
    const int cb = i & 255;
    float res[4];
    #pragma unroll
    for (int j = 0; j < 4; ++j) {
        int c = cb + j;
        float mean = accum[c] * (1.0f / 4096.0f);
        float var  = accum[C2_ + c] * (1.0f / 4096.0f) - mean * mean;
        float rstd = 1.0f / sqrtf(var + 1e-5f);
        float v = gamma[c] * ((vals[j] - mean) * rstd) + beta[c];
        res[j] = fmaxf(v, 0.0f);
    }
    *(float4*)(out + i) = make_float4(res[0], res[1], res[2], res[3]);
}

// ---------------------------------------------------------------------------
extern "C" void kernel_launch(void* const* d_in, const int* in_sizes, int n_in,
                              void* d_out, int out_size, void* d_ws, size_t ws_size,
                              hipStream_t stream) {
    const float* x2    = (const float*)d_in[1];
    const float* xyz1  = (const float*)d_in[2];
    const float* xyz2  = (const float*)d_in[3];
    const float* W1    = (const float*)d_in[4];
    const float* b1    = (const float*)d_in[5];
    const float* gamma = (const float*)d_in[6];
    const float* beta  = (const float*)d_in[7];

    char* ws = (char*)d_ws;
    unsigned short* interp_t = (unsigned short*)(ws);              // 33,554,432 B
    unsigned short* W1b      = (unsigned short*)(ws + 33554432);   //  2,097,152 B
    float*          Zp       = (float*)(ws + 35651584);            // 33,554,432 B (8 slabs)
    float*          accum    = (float*)(ws + 69206016);            //      2,048 B

    knn_interp_kernel <<<2048, 256, 0, stream>>>(xyz1, xyz2, x2, interp_t,
                                                 W1, W1b, accum);
    gemm_kernel       <<<dim3(4, 128, 2), 256, 0, stream>>>(W1b, interp_t, Zp);
    reduce_stats_kernel<<<1024, 256, 0, stream>>>(Zp, b1, accum);
    bn_kernel         <<<1024, 256, 0, stream>>>(Zp, accum, gamma, beta,
                                                 (float*)d_out);
}

// Round 7
// 151.462 us; speedup vs baseline: 1.5978x; 1.5978x over previous
//
#include <hip/hip_runtime.h>
#include <hip/hip_bf16.h>
#include <float.h>

#define B_    16
#define N1_   4096
#define N2_   1024
#define C2_   256
#define OUT_  256
#define K_    4096    // GEMM K == N1
#define SPLITK 8
#define KCH_  (K_ / SPLITK)     // 512
#define ZSLAB 1048576           // floats per partial slab (16*256*256)

typedef short short8 __attribute__((ext_vector_type(8)));
typedef float float4v __attribute__((ext_vector_type(4)));

static __device__ __forceinline__ unsigned short f32_to_bf16_bits(float v) {
    __hip_bfloat16 h = __float2bfloat16(v);
    return *(unsigned short*)&h;
}

static __device__ __forceinline__ void gload16(const void* g, void* l) {
    __builtin_amdgcn_global_load_lds(
        (const __attribute__((address_space(1))) unsigned int*)g,
        (__attribute__((address_space(3))) unsigned int*)l, 16, 0, 0);
}

// ---------------------------------------------------------------------------
// Fused (w1cvt + knn + interp) in ONE dispatch, block-role branch.
// R17 XCD-locality remap (T1): b = ((rem>>9)<<3)|(rem&7) pins all 64
// blocks of batch b to XCD b&7 -> x2[b] L2-resident for the phase-B gather.
// Unchanged in R20.
// ---------------------------------------------------------------------------
#define TPAD 65
struct KnnSh {
    float4 pts[16][65];       // per-slice padded candidates   16.64 KB
    float  pf[64][49];        // per-slice packed top-3 (q-major) 12.54 KB
};
union ShUnion {
    KnnSh a;
    unsigned short tile[C2_][TPAD];   // transpose tile  33.3 KB
};

__global__ __launch_bounds__(256) void knn_interp_kernel(
    const float* __restrict__ xyz1,
    const float* __restrict__ xyz2,
    const float* __restrict__ x2,
    unsigned short* __restrict__ interp_t,
    const float* __restrict__ W1,
    unsigned short* __restrict__ W1b,
    float* __restrict__ accum)
{
    __shared__ ShUnion sh;
    __shared__ float rw[64][3];
    __shared__ int   ri[64][3];

    const int bid = blockIdx.x;
    const int t   = threadIdx.x;

    if (bid < 1024) {   // ---- role: W1 convert (+ accum zero) ----
        if (bid == 0) {
            accum[t] = 0.0f;
            accum[256 + t] = 0.0f;
        }
        const int i = (bid * 256 + t) * 4;
        float4 v = *(const float4*)(W1 + i);
        ushort4 o;
        o.x = f32_to_bf16_bits(v.x);
        o.y = f32_to_bf16_bits(v.y);
        o.z = f32_to_bf16_bits(v.z);
        o.w = f32_to_bf16_bits(v.w);
        *(ushort4*)(W1b + i) = o;
        return;
    }

    // ---- role: knn + interp ----
    // XCD-pinned decode: XCD = bid%8 = rem%8 = b&7 -> same-batch blocks
    // share one XCD's L2 for the x2 gather.
    const int rem = bid - 1024;
    const int b   = ((rem >> 9) << 3) | (rem & 7);
    const int n0  = ((rem >> 3) & 63) * 64;
    const int w   = t >> 6;
    const int l   = t & 63;

    for (int r = 0; r < 4; ++r) {
        int j = r * 256 + t;
        const float* p = xyz2 + ((size_t)b * N2_ + j) * 3;
        float x = p[0], y = p[1], z = p[2];
        sh.a.pts[j >> 6][j & 63] = make_float4(x, y, z, 0.5f * ((x * x + y * y) + z * z));
    }
    __syncthreads();

    const int qg    = l & 15;           // query group: 4 queries per lane
    const int slice = (w << 2) | (l >> 4);   // 16 slices of 64 candidates
    const int jbase = slice << 6;

    // load this lane's 4 queries (12 consecutive floats, 48B aligned)
    const float* qb = xyz1 + ((size_t)b * N1_ + n0 + qg * 4) * 3;
    float4 v0 = ((const float4*)qb)[0];
    float4 v1 = ((const float4*)qb)[1];
    float4 v2 = ((const float4*)qb)[2];
    float qx[4] = {v0.x, v0.w, v1.z, v2.y};
    float qy[4] = {v0.y, v1.x, v1.w, v2.z};
    float qz[4] = {v0.z, v1.y, v2.x, v2.w};

    float ns0[4], ns1[4], ns2[4], ss[4], f[4][3];
    #pragma unroll
    for (int i = 0; i < 4; ++i) {
        ns0[i] = -qx[i]; ns1[i] = -qy[i]; ns2[i] = -qz[i];
        ss[i]  = (qx[i] * qx[i] + qy[i] * qy[i]) + qz[i] * qz[i];
        f[i][0] = FLT_MAX; f[i][1] = FLT_MAX; f[i][2] = FLT_MAX;
    }

    #pragma unroll 2
    for (int jj = 0; jj < 64; ++jj) {
        float4 pq = sh.a.pts[slice][jj];
        int j = jbase + jj;
        #pragma unroll
        for (int i = 0; i < 4; ++i) {
            float acc = fmaf(ns0[i], pq.x, pq.w);
            acc = fmaf(ns1[i], pq.y, acc);
            acc = fmaf(ns2[i], pq.z, acc);
            float dk = fmaxf(fmaf(2.0f, acc, ss[i]), 0.0f);
            float fp = __int_as_float((__float_as_int(dk) & 0xFFFFFC00) | j);
            float nf0 = fminf(fp, f[i][0]);
            float nf1 = __builtin_amdgcn_fmed3f(fp, f[i][0], f[i][1]);
            float nf2 = fminf(f[i][2], fmaxf(fp, f[i][1]));
            f[i][0] = nf0; f[i][1] = nf1; f[i][2] = nf2;
        }
    }

    #pragma unroll
    for (int i = 0; i < 4; ++i)
    #pragma unroll
    for (int r = 0; r < 3; ++r)
        sh.a.pf[qg * 4 + i][slice * 3 + r] = f[i][r];
    __syncthreads();

    if (w == 0) {
        float g0 = FLT_MAX, g1 = FLT_MAX, g2 = FLT_MAX;
        #pragma unroll 4
        for (int s = 0; s < 16; ++s)
        #pragma unroll
        for (int r = 0; r < 3; ++r) {
            float fp = sh.a.pf[l][s * 3 + r];
            float n0v = fminf(fp, g0);
            float n1v = __builtin_amdgcn_fmed3f(fp, g0, g1);
            float n2v = fminf(g2, fmaxf(fp, g1));
            g0 = n0v; g1 = n1v; g2 = n2v;
        }
        int j0 = __float_as_int(g0) & 1023;
        int j1 = __float_as_int(g1) & 1023;
        int j2 = __float_as_int(g2) & 1023;
        const float4 p0 = sh.a.pts[j0 >> 6][j0 & 63];
        const float4 p1 = sh.a.pts[j1 >> 6][j1 & 63];
        const float4 p2 = sh.a.pts[j2 >> 6][j2 & 63];
        // recompute exact distances for THIS query (lane l = local query id)
        const float* q = xyz1 + ((size_t)b * N1_ + n0 + l) * 3;
        const float s0 = q[0], s1 = q[1], s2 = q[2];
        const float ssl = (s0 * s0 + s1 * s1) + s2 * s2;
        float dd0 = ssl + 2.0f * (p0.w - ((s0 * p0.x + s1 * p0.y) + s2 * p0.z));
        float dd1 = ssl + 2.0f * (p1.w - ((s0 * p1.x + s1 * p1.y) + s2 * p1.z));
        float dd2 = ssl + 2.0f * (p2.w - ((s0 * p2.x + s1 * p2.y) + s2 * p2.z));
        float r0 = 1.0f / (dd0 + 1e-8f);
        float r1 = 1.0f / (dd1 + 1e-8f);
        float r2 = 1.0f / (dd2 + 1e-8f);
        float sden = (r0 + r1) + r2;
        rw[l][0] = r0 / sden;  rw[l][1] = r1 / sden;  rw[l][2] = r2 / sden;
        ri[l][0] = j0;         ri[l][1] = j1;         ri[l][2] = j2;
    }
    __syncthreads();   // rw/ri ready; pts/pf dead -> tile may alias

    for (int p = 0; p < 16; ++p) {
        int nl = p * 4 + w;
        float w0 = rw[nl][0], w1 = rw[nl][1], w2 = rw[nl][2];
        int i0g = ri[nl][0], i1g = ri[nl][1], i2g = ri[nl][2];
        const float4 va = ((const float4*)(x2 + ((size_t)b * N2_ + i0g) * C2_))[l];
        const float4 vb = ((const float4*)(x2 + ((size_t)b * N2_ + i1g) * C2_))[l];
        const float4 vc = ((const float4*)(x2 + ((size_t)b * N2_ + i2g) * C2_))[l];
        float fa[4] = {va.x, va.y, va.z, va.w};
        float fb[4] = {vb.x, vb.y, vb.z, vb.w};
        float fc[4] = {vc.x, vc.y, vc.z, vc.w};
        #pragma unroll
        for (int i = 0; i < 4; ++i) {
            float v = w0 * fa[i];
            v = fmaf(w1, fb[i], v);
            v = fmaf(w2, fc[i], v);
            sh.tile[l * 4 + i][nl] = f32_to_bf16_bits(v);
        }
    }
    __syncthreads();

    for (int r = 0; r < 64; ++r) {
        int c = r * 4 + w;
        interp_t[((size_t)b * C2_ + c) * K_ + n0 + l] = sh.tile[c][l];
    }
}

// ---------------------------------------------------------------------------
// Kernel 3: split-K GEMM, tile 128(o) x 64(c), BK=64 -> 8 iterations.
// global_load_lds width-16 into LINEAR LDS with XOR chunk-swizzle (R16).
// R17 grid (4c, 128bk, 2o): o-tile partners 512 apart (== 0 mod 8) -> same
// XCD -> B fetched once. Unchanged in R20.
// ---------------------------------------------------------------------------
__global__ __launch_bounds__(256) void gemm_kernel(
    const unsigned short* __restrict__ W1b,
    const unsigned short* __restrict__ interp_t,
    float* __restrict__ Zp)
{
    __shared__ unsigned short Alds[128 * 64];   // 16 KB linear
    __shared__ unsigned short Blds[64 * 64];    //  8 KB linear
    const int b  = blockIdx.y >> 3;
    const int kc = blockIdx.y & 7;
    const int o0 = blockIdx.z * 128;
    const int c0 = blockIdx.x * 64;
    const int t = threadIdx.x;
    const int w = t >> 6, l = t & 63;
    const int ob = (w >> 1) * 64, cb = (w & 1) * 32;
    const int m = l & 15, kq = l >> 4;

    const int rs  = l >> 3;        // row within 8-row segment
    const int ch  = l & 7;         // 16B chunk within 128B row
    const int sch = ch ^ rs;       // swizzled source chunk

    const unsigned short* Abase = W1b + (size_t)o0 * K_ + kc * KCH_ + sch * 8;
    const unsigned short* Bbase = interp_t + ((size_t)b * C2_ + c0) * K_ + kc * KCH_ + sch * 8;

    float4v acc[4][2] = {};

    for (int kk = 0; kk < KCH_; kk += 64) {
        // stage A: 16 segments of 1KB, wave w does s = w, w+4, w+8, w+12
        #pragma unroll
        for (int i = 0; i < 4; ++i) {
            int s = w + i * 4;
            gload16(Abase + (size_t)(s * 8 + rs) * K_ + kk, &Alds[s * 512 + l * 8]);
        }
        // stage B: 8 segments, wave w does s = w, w+4
        #pragma unroll
        for (int i = 0; i < 2; ++i) {
            int s = w + i * 4;
            gload16(Bbase + (size_t)(s * 8 + rs) * K_ + kk, &Blds[s * 512 + l * 8]);
        }
        __syncthreads();

        #pragma unroll
        for (int ks = 0; ks < 64; ks += 32) {
            const int swz = ((kq + (ks >> 3)) ^ (m & 7)) << 3;
            short8 bf0 = *(const short8*)&Blds[(cb + m) * 64 + swz];
            short8 bf1 = *(const short8*)&Blds[(cb + 16 + m) * 64 + swz];
            #pragma unroll
            for (int mi = 0; mi < 4; ++mi) {
                short8 af = *(const short8*)&Alds[(ob + mi * 16 + m) * 64 + swz];
                acc[mi][0] = __builtin_amdgcn_mfma_f32_16x16x32_bf16(af, bf0, acc[mi][0], 0, 0, 0);
                acc[mi][1] = __builtin_amdgcn_mfma_f32_16x16x32_bf16(af, bf1, acc[mi][1], 0, 0, 0);
            }
        }
        __syncthreads();
    }

    float* Zslab = Zp + (size_t)kc * ZSLAB;
    #pragma unroll
    for (int mi = 0; mi < 4; ++mi)
    #pragma unroll
    for (int ni = 0; ni < 2; ++ni)
    #pragma unroll
    for (int r = 0; r < 4; ++r) {
        int o = o0 + ob + mi * 16 + kq * 4 + r;
        int c = c0 + cb + ni * 16 + m;
        Zslab[((size_t)b * OUT_ + o) * C2_ + c] = acc[mi][ni][r];
    }
}

// ---------------------------------------------------------------------------
// Kernel 4 (R20): bandwidth-shaped reduce, NO atomics.
// R19 post-mortem: loads were fine (slabs L3-resident, FETCH 16MB); the
// 103.8us was the 1024-deep same-address atomicAdd chain (1024 x ~100ns
// per address at the device coherence point). Replace with a two-stage
// tree: each block writes its 512 per-channel partials to a PRIVATE row
// partials[bid][512] (two coalesced dwordx4 stores/thread, 2 MB total) —
// zero atomics, deterministic. Stage B (stats_final) sums the 1024 rows.
// Load structure identical to R19: 1 float4/thread, 8 coalesced slab
// loads, bias-first order, final Z written to slab 0.
// ---------------------------------------------------------------------------
__global__ __launch_bounds__(256) void reduce_stats_kernel(
    float* __restrict__ Zp, const float* __restrict__ b1,
    float* __restrict__ partials)
{
    __shared__ float red_s[256][4];
    __shared__ float red_q[256][4];
    const int t  = threadIdx.x;
    const int i4 = blockIdx.x * 256 + t;       // float4 index, 0..262143
    const int o  = (i4 >> 6) & 255;

    float bb = b1[o];
    float4 v = make_float4(bb, bb, bb, bb);
    #pragma unroll
    for (int sl = 0; sl < SPLITK; ++sl) {
        float4 p = *((const float4*)Zp + (size_t)sl * (ZSLAB / 4) + i4);
        v.x += p.x; v.y += p.y; v.z += p.z; v.w += p.w;
    }
    *((float4*)Zp + i4) = v;                   // final Z into slab 0

    red_s[t][0] = v.x;       red_s[t][1] = v.y;
    red_s[t][2] = v.z;       red_s[t][3] = v.w;
    red_q[t][0] = v.x * v.x; red_q[t][1] = v.y * v.y;
    red_q[t][2] = v.z * v.z; red_q[t][3] = v.w * v.w;
    __syncthreads();

    if (t < 64) {
        float4 s4, q4;
        float* sp = (float*)&s4;
        float* qp = (float*)&q4;
        #pragma unroll
        for (int j = 0; j < 4; ++j) {
            sp[j] = red_s[t][j] + red_s[t + 64][j] + red_s[t + 128][j] + red_s[t + 192][j];
            qp[j] = red_q[t][j] + red_q[t + 64][j] + red_q[t + 128][j] + red_q[t + 192][j];
        }
        // private partial row: [0:256) channel sums, [256:512) channel sumsq
        *(float4*)(partials + (size_t)blockIdx.x * 512 + t * 4)       = s4;
        *(float4*)(partials + (size_t)blockIdx.x * 512 + 256 + t * 4) = q4;
    }
}

// ---------------------------------------------------------------------------
// Kernel 4b (R20): column-sum of the 1024 partial rows -> accum[512].
// Block k owns stat k; thread t sums rows {t, t+256, t+512, t+768}; LDS
// tree + wave shfl reduce; single plain store. No atomics anywhere.
// ---------------------------------------------------------------------------
__global__ __launch_bounds__(256) void stats_final_kernel(
    const float* __restrict__ partials, float* __restrict__ accum)
{
    __shared__ float red[256];
    const int k = blockIdx.x;      // 0..511
    const int t = threadIdx.x;
    float s = 0.0f;
    #pragma unroll
    for (int i = 0; i < 4; ++i)
        s += partials[(size_t)(t + 256 * i) * 512 + k];
    red[t] = s;
    __syncthreads();
    if (t < 128) red[t] += red[t + 128];
    __syncthreads();
    if (t < 64) {
        float v = red[t] + red[t + 64];
        #pragma unroll
        for (int off = 32; off > 0; off >>= 1)
            v += __shfl_down(v, off);
        if (t == 0) accum[k] = v;
    }
}

// ---------------------------------------------------------------------------
// Kernel 5: normalize + affine + ReLU + f32 store (reads final Z = slab 0).
// ---------------------------------------------------------------------------
__global__ __launch_bounds__(256) void bn_kernel(
    const float* __restrict__ Z, const float* __restrict__ accum,
    const float* __restrict__ gamma, const float* __restrict__ beta,
    float* __restrict__ out)
{
    const int i = (blockIdx.x * 256 + threadIdx.x) * 4;
    float4 z = *(const float4*)(Z + i);
    float vals[4] = {z.x, z.y, z.z, z.w};
    const int cb = i & 255;
    float res[4];
    #pragma unroll
    for (int j = 0; j < 4; ++j) {
        int c = cb + j;
        float mean = accum[c] * (1.0f / 4096.0f);
        float var  = accum[C2_ + c] * (1.0f / 4096.0f) - mean * mean;
        float rstd = 1.0f / sqrtf(var + 1e-5f);
        float v = gamma[c] * ((vals[j] - mean) * rstd) + beta[c];
        res[j] = fmaxf(v, 0.0f);
    }
    *(float4*)(out + i) = make_float4(res[0], res[1], res[2], res[3]);
}

// ---------------------------------------------------------------------------
extern "C" void kernel_launch(void* const* d_in, const int* in_sizes, int n_in,
                              void* d_out, int out_size, void* d_ws, size_t ws_size,
                              hipStream_t stream) {
    const float* x2    = (const float*)d_in[1];
    const float* xyz1  = (const float*)d_in[2];
    const float* xyz2  = (const float*)d_in[3];
    const float* W1    = (const float*)d_in[4];
    const float* b1    = (const float*)d_in[5];
    const float* gamma = (const float*)d_in[6];
    const float* beta  = (const float*)d_in[7];

    char* ws = (char*)d_ws;
    unsigned short* interp_t = (unsigned short*)(ws);              // 33,554,432 B
    unsigned short* W1b      = (unsigned short*)(ws + 33554432);   //  2,097,152 B
    float*          Zp       = (float*)(ws + 35651584);            // 33,554,432 B (8 slabs)
    float*          accum    = (float*)(ws + 69206016);            //      2,048 B
    float*          partials = (float*)(ws + 69210112);            //  2,097,152 B

    knn_interp_kernel <<<2048, 256, 0, stream>>>(xyz1, xyz2, x2, interp_t,
                                                 W1, W1b, accum);
    gemm_kernel       <<<dim3(4, 128, 2), 256, 0, stream>>>(W1b, interp_t, Zp);
    reduce_stats_kernel<<<1024, 256, 0, stream>>>(Zp, b1, partials);
    stats_final_kernel<<<512, 256, 0, stream>>>(partials, accum);
    bn_kernel         <<<1024, 256, 0, stream>>>(Zp, accum, gamma, beta,
                                                 (float*)d_out);
}